// Round 8
// baseline (414.170 us; speedup 1.0000x reference)
//
#include <hip/hip_runtime.h>

// AlphaNet R11: full-row staging, 1 barrier per pass, h-parallel lanes.
//   apass<P>: 2048 blocks x 32 samples. Stage FULL rows [32][486] (61KB,
//     float2 global loads, line-exact) ONCE -> single __syncthreads -> all
//     windows computed with no further barriers (ds_reads pipeline freely).
//     lane=(h<<5)|sm: each lane owns (sample, half) = 3 windows; wave_sum64
//     spans 32 samples x 2 halves so per-(b,h) max stats flush correctly.
//     Wave subtasks: w0 corr pairs 0-13+xb4 f0-3, w1 corr 14-27+xb4 f4-7,
//     w2 bc f0-3, w3 bc f4-7.
//   partial[304][2048] all-slots-written (no memset), plain stores:
//     row ch: S | 76+ch: Q | 152+ch: sum of per-(b,h) max | 228+ch: sumsq.
//   kR: 304 blocks x 2048-wide reduce -> stats.
//   k2: fused BN fold (params in LDS; w1s rows + c0), unchanged from R10.
//   apass<1>: A[30] per lane; combine 4 waves x 2 halves in LDS (7.7KB,
//     reuses sx), relu dot w2 -> out[bid*32+sm].
// __launch_bounds__(256,2): cap 128 (R9-verified law cap~=256/w); demand ~106.
// ws floats: [0,304) stats | [608,640) c0 | [640,18880) w1s |
//            [18880,+622592) partial

#define EPS_F    1e-8f
#define BN_EPS_F 1e-5f
#define LSTR 486   // words/sample; stride mod 32 = 6 -> <=2 lanes/bank (free, m136)

__device__ __forceinline__ float frcp(float x) {
  return __builtin_amdgcn_rcpf(x);
}

template<int Ctrl, int RowMask>
__device__ __forceinline__ float dpp_mov0(float v) {
  return __int_as_float(__builtin_amdgcn_update_dpp(
      0, __float_as_int(v), Ctrl, RowMask, 0xf, true));
}
// wave64 sum; result valid in lane 63. VALU-only.
__device__ __forceinline__ float wave_sum64(float v) {
  v += dpp_mov0<0x111, 0xf>(v);
  v += dpp_mov0<0x112, 0xf>(v);
  v += dpp_mov0<0x114, 0xf>(v);
  v += dpp_mov0<0x118, 0xf>(v);
  v += dpp_mov0<0x142, 0xa>(v);
  v += dpp_mov0<0x143, 0xc>(v);
  return v;
}

// pair p -> (i,j), p in triu(k=1) row-major order (matches IU/JU)
constexpr int PI_[28] = {0,0,0,0,0,0,0, 1,1,1,1,1,1, 2,2,2,2,2, 3,3,3,3, 4,4,4, 5,5, 6};
constexpr int PJ_[28] = {1,2,3,4,5,6,7, 2,3,4,5,6,7, 3,4,5,6,7, 4,5,6,7, 5,6,7, 6,7, 7};

// ---- corr subtask over this lane's 3 windows ----
// bx -> lane's (sample,half) base. pass1 rows: (ch*6 + h*3 + wl), max 456+ch*2+h.
template<int PASS, int W>
__device__ __forceinline__ void corr_full(
    const float* __restrict__ bx, const int h,
    const float* __restrict__ w1s,
    float* __restrict__ S, float* __restrict__ Q, float* __restrict__ M,
    float* __restrict__ A)
{
  constexpr int PLO = W * 14;
  constexpr int FLO = W * 4;
  #pragma unroll 1
  for (int wl = 0; wl < 3; ++wl) {
    float sum[8], SD[8], SP[14];
    #pragma unroll
    for (int f = 0; f < 8; ++f) { sum[f] = 0.f; SD[f] = 0.f; }
    #pragma unroll
    for (int k = 0; k < 14; ++k) SP[k] = 0.f;
    #pragma unroll
    for (int tp = 0; tp < 5; ++tp) {
      float2 x2[8];
      #pragma unroll
      for (int f = 0; f < 8; ++f)
        x2[f] = *reinterpret_cast<const float2*>(bx + f*60 + wl*10 + tp*2);
      #pragma unroll
      for (int f = 0; f < 8; ++f) {
        sum[f] += x2[f].x + x2[f].y;
        SD[f] = fmaf(x2[f].x, x2[f].x, fmaf(x2[f].y, x2[f].y, SD[f]));
      }
      #pragma unroll
      for (int k = 0; k < 14; ++k) {
        const int i = PI_[PLO + k], j = PJ_[PLO + k];
        SP[k] = fmaf(x2[i].x, x2[j].x, fmaf(x2[i].y, x2[j].y, SP[k]));
      }
    }
    float mu[8], sd[8];
    #pragma unroll
    for (int f = 0; f < 8; ++f) {
      mu[f] = sum[f] * 0.1f;
      sd[f] = sqrtf(fmaf(-mu[f], mu[f], SD[f] * 0.1f) + EPS_F);
    }
    #pragma unroll
    for (int k = 0; k < 14; ++k) {
      const int i = PI_[PLO + k], j = PJ_[PLO + k];
      float cov = fmaf(-mu[i], mu[j], SP[k] * 0.1f);
      float v = cov * frcp(fmaf(sd[i], sd[j], EPS_F));
      M[k] = fmaxf(M[k], v);
      if (PASS == 0) { S[k] += v; Q[k] = fmaf(v, v, Q[k]); }
      else {
        const float* wr = w1s + ((PLO + k)*6 + h*3 + wl) * 30;  // uniform -> s_load
        #pragma unroll
        for (int j2 = 0; j2 < 30; ++j2) A[j2] = fmaf(v, wr[j2], A[j2]);
      }
    }
    #pragma unroll
    for (int q = 0; q < 4; ++q) {
      const int k = 14 + q;
      float v = mu[FLO + q] * frcp(sd[FLO + q] + EPS_F);
      M[k] = fmaxf(M[k], v);
      if (PASS == 0) { S[k] += v; Q[k] = fmaf(v, v, Q[k]); }
      else {
        const float* wr = w1s + ((28 + FLO + q)*6 + h*3 + wl) * 30;
        #pragma unroll
        for (int j2 = 0; j2 < 30; ++j2) A[j2] = fmaf(v, wr[j2], A[j2]);
      }
    }
  }
  if (PASS == 1) {
    #pragma unroll
    for (int k = 0; k < 18; ++k) {
      const int ch = (k < 14) ? (PLO + k) : (28 + FLO + (k - 14));
      const float* wr = w1s + (456 + ch*2 + h) * 30;
      #pragma unroll
      for (int j2 = 0; j2 < 30; ++j2) A[j2] = fmaf(M[k], wr[j2], A[j2]);
    }
  }
}

// ---- bc subtask over this lane's 3 windows (runtime G) ----
template<int PASS>
__device__ __forceinline__ void bc_full(
    const float* __restrict__ bx, const int h, const int G,
    const float* __restrict__ cw, const float* __restrict__ cb,
    const float* __restrict__ w1s,
    float* __restrict__ S, float* __restrict__ Q, float* __restrict__ M,
    float* __restrict__ A)
{
  const int FLO = G * 4;
  #pragma unroll 1
  for (int wl = 0; wl < 3; ++wl) {
    #pragma unroll
    for (int q = 0; q < 4; ++q) {
      const int f = FLO + q;
      float2 x2[5];
      #pragma unroll
      for (int tp = 0; tp < 5; ++tp)
        x2[tp] = *reinterpret_cast<const float2*>(bx + f*60 + wl*10 + tp*2);
      float wsm = 0.f;
      #pragma unroll
      for (int tp = 0; tp < 5; ++tp)
        wsm = fmaf(x2[tp].x, (float)(2*tp+1) * (1.f/55.f),
              fmaf(x2[tp].y, (float)(2*tp+2) * (1.f/55.f), wsm));
      {
        const int k = q*5;
        M[k] = fmaxf(M[k], wsm);
        if (PASS == 0) { S[k] += wsm; Q[k] = fmaf(wsm, wsm, Q[k]); }
        else {
          const float* wr = w1s + ((36 + f)*6 + h*3 + wl) * 30;
          #pragma unroll
          for (int j2 = 0; j2 < 30; ++j2) A[j2] = fmaf(wsm, wr[j2], A[j2]);
        }
      }
      #pragma unroll
      for (int o = 0; o < 4; ++o) {
        float cv = cb[o];
        #pragma unroll
        for (int tp = 0; tp < 5; ++tp)
          cv = fmaf(x2[tp].x, cw[o*10 + 2*tp], fmaf(x2[tp].y, cw[o*10 + 2*tp + 1], cv));
        const int k = q*5 + 1 + o;
        M[k] = fmaxf(M[k], cv);
        if (PASS == 0) { S[k] += cv; Q[k] = fmaf(cv, cv, Q[k]); }
        else {
          const float* wr = w1s + ((44 + o*8 + f)*6 + h*3 + wl) * 30;
          #pragma unroll
          for (int j2 = 0; j2 < 30; ++j2) A[j2] = fmaf(cv, wr[j2], A[j2]);
        }
      }
    }
  }
  if (PASS == 1) {
    #pragma unroll
    for (int k = 0; k < 20; ++k) {
      const int f = FLO + k/5, c = k%5;
      const int ch = (c == 0) ? (36 + f) : (44 + (c-1)*8 + f);
      const float* wr = w1s + (456 + ch*2 + h) * 30;
      #pragma unroll
      for (int j2 = 0; j2 < 30; ++j2) A[j2] = fmaf(M[k], wr[j2], A[j2]);
    }
  }
}

// ================= main passes =================

template<int PASS>
__global__ void __launch_bounds__(256, 2)
apass(const float* __restrict__ xb, const float* __restrict__ cw,
      const float* __restrict__ cb, const float* __restrict__ w1s,
      const float* __restrict__ c0, const float* __restrict__ w2,
      const float* __restrict__ b2, float* __restrict__ partial,
      float* __restrict__ out)
{
  __shared__ float sx[32 * LSTR];   // 60.75 KB -> 2 blocks/CU
  const int tid  = threadIdx.x;
  const int wave = __builtin_amdgcn_readfirstlane(tid >> 6);
  const int lane = tid & 63;
  const int sm   = lane & 31;
  const int h    = lane >> 5;
  const int bid  = blockIdx.x;

  // ---- stage 32 full rows, contiguous float2, batched loads then writes ----
  const float* gb = xb + (size_t)bid * (32 * 480);
  {
    float2 t[30];
    #pragma unroll
    for (int k = 0; k < 30; ++k)
      t[k] = *reinterpret_cast<const float2*>(gb + (size_t)(k*256 + tid) * 2);
    #pragma unroll
    for (int k = 0; k < 30; ++k) {
      const int g2  = k*256 + tid;
      const int smw = g2 / 240;
      const int c2  = g2 - smw*240;
      *reinterpret_cast<float2*>(sx + smw*LSTR + c2*2) = t[k];
    }
  }
  __syncthreads();   // the ONLY pre-compute barrier

  float A[30], S[20], Q[20], M[20];
  if (PASS == 0) {
    #pragma unroll
    for (int k = 0; k < 20; ++k) { S[k] = 0.f; Q[k] = 0.f; }
  } else {
    #pragma unroll
    for (int j = 0; j < 30; ++j) A[j] = 0.f;
  }
  #pragma unroll
  for (int k = 0; k < 20; ++k) M[k] = -3.0e38f;

  const float* bx = sx + sm * LSTR + h * 30;

  if      (wave == 0) corr_full<PASS,0>(bx, h, w1s, S, Q, M, A);
  else if (wave == 1) corr_full<PASS,1>(bx, h, w1s, S, Q, M, A);
  else                bc_full<PASS>(bx, h, wave - 2, cw, cb, w1s, S, Q, M, A);

  if (PASS == 0) {
    // block-end flush: per owned channel, 4 wave-sums, lane-63 plain stores
    const int nch = (wave < 2) ? 18 : 20;
    #pragma unroll
    for (int k = 0; k < 20; ++k) {
      if (k < nch) {
        int ch;
        if (wave < 2) ch = (k < 14) ? (wave*14 + k) : (28 + wave*4 + (k - 14));
        else {
          const int f = (wave - 2)*4 + k/5, c = k%5;
          ch = (c == 0) ? (36 + f) : (44 + (c-1)*8 + f);
        }
        float t0 = wave_sum64(S[k]);
        float t1 = wave_sum64(Q[k]);
        float t2 = wave_sum64(M[k]);          // sum over 32 samples x 2 halves
        float t3 = wave_sum64(M[k] * M[k]);
        if (lane == 63) {
          partial[(size_t)(      ch) * 2048 + bid] = t0;
          partial[(size_t)( 76 + ch) * 2048 + bid] = t1;
          partial[(size_t)(152 + ch) * 2048 + bid] = t2;
          partial[(size_t)(228 + ch) * 2048 + bid] = t3;
        }
      }
    }
  } else {
    // combine 4 waves x 2 halves -> 32 outputs (reuses sx: 4*64*31 = 7.7KB)
    __syncthreads();   // all waves done reading sx
    #pragma unroll
    for (int j = 0; j < 30; ++j) sx[(wave*64 + lane)*31 + j] = A[j];
    __syncthreads();
    if (tid < 32) {
      float t0 = b2[0];
      #pragma unroll
      for (int j = 0; j < 30; ++j) {
        float hh = c0[j];
        #pragma unroll
        for (int wv = 0; wv < 4; ++wv)
          hh += sx[(wv*64 + tid)*31 + j] + sx[(wv*64 + 32 + tid)*31 + j];
        t0 = fmaf(w2[j], fmaxf(hh, 0.f), t0);
      }
      out[bid * 32 + tid] = t0;
    }
  }
}

// ---- reduce partial rows -> stats (no atomics) ----
__global__ void __launch_bounds__(256)
kR(const float* __restrict__ partial, float* __restrict__ stats) {
  const int r = blockIdx.x;
  const float* p = partial + (size_t)r * 2048;
  const int tid = threadIdx.x;
  float s = 0.f;
  #pragma unroll
  for (int i = 0; i < 8; ++i) s += p[i*256 + tid];
  s = wave_sum64(s);
  __shared__ float ls[4];
  if ((tid & 63) == 63) ls[tid >> 6] = s;
  __syncthreads();
  if (tid == 0) stats[r] = (ls[0] + ls[1]) + (ls[2] + ls[3]);
}

// ================= fused BN-fold kernel =================
// 39 blocks: each recomputes BN params in LDS; blocks 0..37 scale 16 w1
// rows each into w1s; block 38 computes c0 (8-lane shfl reduce). No atomics.
__global__ void __launch_bounds__(256)
k2(const float* __restrict__ stats,
   const float* __restrict__ bn1g, const float* __restrict__ bn1b,
   const float* __restrict__ bn4g, const float* __restrict__ bn4b,
   const float* __restrict__ bn6g, const float* __restrict__ bn6b,
   const float* __restrict__ bn9g, const float* __restrict__ bn9b,
   const float* __restrict__ bnmg, const float* __restrict__ bnmb,
   const float* __restrict__ w1, const float* __restrict__ b1,
   float* __restrict__ w1s, float* __restrict__ c0) {
  __shared__ float P0[76], P1[76], P2[76], P3[76];
  const int tid = threadIdx.x;
  if (tid < 76) {
    const int c = tid;
    float g, b;
    if      (c < 28) { g = bn1g[c];    b = bn1b[c];    }
    else if (c < 36) { g = bn4g[c-28]; b = bn4b[c-28]; }
    else if (c < 44) { g = bn6g[c-36]; b = bn6b[c-36]; }
    else             { g = bn9g[c-44]; b = bn9b[c-44]; }
    const float in1 = 1.0f / (65536.0f * 6.0f);
    const float in2 = 1.0f / (65536.0f * 2.0f);
    float mean = stats[c] * in1;
    float var  = stats[76 + c] * in1 - mean * mean;
    float r    = rsqrtf(var + BN_EPS_F);
    float sc1  = g * r;
    float sh1  = b - mean * sc1;
    float mmr  = stats[152 + c] * in2;
    float vmr  = stats[228 + c] * in2 - mmr * mmr;
    float meanm = sc1 * mmr + sh1;
    float varm  = sc1 * sc1 * vmr;
    float rm  = rsqrtf(varm + BN_EPS_F);
    float scm = bnmg[c] * rm;
    float shm = bnmb[c] - meanm * scm;
    P0[c] = sc1; P1[c] = sh1; P2[c] = scm; P3[c] = shm;
  }
  __syncthreads();

  if (blockIdx.x < 38) {
    const int r0 = blockIdx.x * 16;
    for (int e = tid; e < 16*30; e += 256) {
      const int r = r0 + e / 30, j = e % 30;
      float sc;
      if (r < 456) sc = P0[r / 6];
      else { const int c = (r - 456) >> 1; sc = P0[c] * P2[c]; }
      w1s[r * 30 + j] = sc * w1[j * 608 + r];
    }
  } else {
    const int j = tid >> 3, l8 = tid & 7;
    if (j < 30) {
      float s = 0.f;
      for (int r = l8; r < 608; r += 8) {
        float cst;
        if (r < 456) cst = P1[r / 6];
        else {
          const int c = (r - 456) >> 1;
          cst = fmaf(P2[c], P1[c], P3[c]);
        }
        s = fmaf(cst, w1[j * 608 + r], s);
      }
      s += __shfl_xor(s, 1, 64);
      s += __shfl_xor(s, 2, 64);
      s += __shfl_xor(s, 4, 64);
      if (l8 == 0) c0[j] = s + b1[j];
    }
  }
}

// ================= launch =================

extern "C" void kernel_launch(void* const* d_in, const int* in_sizes, int n_in,
                              void* d_out, int out_size, void* d_ws, size_t ws_size,
                              hipStream_t stream) {
  (void)in_sizes; (void)n_in; (void)out_size; (void)ws_size;
  const float* xb   = (const float*)d_in[0];
  const float* cw   = (const float*)d_in[1];
  const float* cb   = (const float*)d_in[2];
  const float* bn1g = (const float*)d_in[3];
  const float* bn1b = (const float*)d_in[4];
  const float* bn4g = (const float*)d_in[5];
  const float* bn4b = (const float*)d_in[6];
  const float* bn6g = (const float*)d_in[7];
  const float* bn6b = (const float*)d_in[8];
  const float* bn9g = (const float*)d_in[9];
  const float* bn9b = (const float*)d_in[10];
  const float* bnmg = (const float*)d_in[11];
  const float* bnmb = (const float*)d_in[12];
  const float* w1   = (const float*)d_in[13];
  const float* b1   = (const float*)d_in[14];
  const float* w2   = (const float*)d_in[15];
  const float* b2   = (const float*)d_in[16];

  float* out     = (float*)d_out;
  float* ws      = (float*)d_ws;
  float* stats   = ws;          // 304
  float* c0      = ws + 608;    // 32
  float* w1s     = ws + 640;    // 608*30
  float* partial = ws + 18880;  // 304*2048

  apass<0><<<2048, 256, 0, stream>>>(xb, cw, cb, nullptr, nullptr, nullptr,
                                     nullptr, partial, nullptr);
  kR<<<304, 256, 0, stream>>>(partial, stats);
  k2<<<39, 256, 0, stream>>>(stats, bn1g, bn1b, bn4g, bn4b, bn6g, bn6b,
                             bn9g, bn9b, bnmg, bnmb, w1, b1, w1s, c0);
  apass<1><<<2048, 256, 0, stream>>>(xb, cw, cb, w1s, c0, w2, b2,
                                     nullptr, out);
}